// Round 9
// baseline (206.101 us; speedup 1.0000x reference)
//
#include <hip/hip_runtime.h>
#include <hip/hip_fp16.h>

#define BB 32
#define NN 512
#define DD 256
#define NEG_INF -9e15f

typedef _Float16 half8 __attribute__((ext_vector_type(8)));
typedef float v4f __attribute__((ext_vector_type(4)));
typedef float f4v __attribute__((ext_vector_type(4)));

// Fragment-swizzled layouts (16x16x32 MFMA, lane = q*16+c reads 16B at laneID*16B):
//  h16f : element h[b][n][d] at ((b*32 + n/16)*8 + d/32)*512 + ((d%32)/8)*128 + (n%16)*8 + d%8
//  h16tf: element h[b][j][d] at ((b*16 + d/16)*16 + j/32)*512 + ((j%32)/8)*128 + (d%16)*8 + j%8

// ---------------- pre-kernel: fp32 -> fp16 convert into swizzled layouts ----------------
__global__ __launch_bounds__(128) void cvt_kernel(const float* __restrict__ h,
                                                  _Float16* __restrict__ h16f,
                                                  _Float16* __restrict__ h16tf) {
    __shared__ _Float16 tile[32][36];
    const int d0 = blockIdx.x * 32;
    const int n0 = blockIdx.y * 32;
    const int b  = blockIdx.z;
    const int t  = threadIdx.x;

    const int nl = t >> 2;          // 0..31
    const int dq = (t & 3) * 8;     // 0,8,16,24
    const float* src = h + ((size_t)b * NN + (n0 + nl)) * DD + d0 + dq;
    f4v v0 = *(const f4v*)(src);
    f4v v1 = *(const f4v*)(src + 4);
    half8 hv = { (_Float16)v0.x, (_Float16)v0.y, (_Float16)v0.z, (_Float16)v0.w,
                 (_Float16)v1.x, (_Float16)v1.y, (_Float16)v1.z, (_Float16)v1.w };

    {
        const size_t off = ((size_t)(b * 32 + ((n0 + nl) >> 4)) * 8 + (d0 >> 5)) * 512
                         + (dq >> 3) * 128 + ((n0 + nl) & 15) * 8;
        *(half8*)(h16f + off) = hv;
    }
    *(half8*)(&tile[nl][dq]) = hv;
    __syncthreads();

    const int dl = t >> 2;          // 0..31
    const int nq = (t & 3) * 8;     // 0,8,16,24
    half8 o = { tile[nq][dl],     tile[nq + 1][dl], tile[nq + 2][dl], tile[nq + 3][dl],
                tile[nq + 4][dl], tile[nq + 5][dl], tile[nq + 6][dl], tile[nq + 7][dl] };
    {
        const size_t off = ((size_t)(b * 16 + ((d0 + dl) >> 4)) * 16 + (n0 >> 5)) * 512
                         + (nq >> 3) * 128 + ((d0 + dl) & 15) * 8;
        *(half8*)(h16tf + off) = o;
    }
}

// ---------------- fused GAT kernel ----------------
// Grid: BB*(NN/16) = 1024 blocks of 256 threads. Block = (b, 16-row i-block).
// XCD swizzle: XCD x (= blk&7 under round-robin dispatch) owns batches 4x..4x+3.
// R8 skeleton (no rotating pipelines — those spill). New: chunked batch loads:
// phase 1 = 8 chunks of 16 j with all 8 B-frags loaded up-front (8-deep vmcnt);
// phase 3 = ks pairs with 8 loads up-front.
__global__ __launch_bounds__(256, 4) void gat_kernel(
    const _Float16* __restrict__ h16f,   // swizzled [B][N/16][D/32][4][16][8]
    const _Float16* __restrict__ h16tf,  // swizzled [B][D/16][N/32][4][16][8]
    const int* __restrict__ adj,         // [B][N][N]
    const float* __restrict__ a0, const float* __restrict__ a1,
    const float* __restrict__ a2, const float* __restrict__ a3,
    float* __restrict__ out)             // [B][N][D]
{
    // union: phase 1 -> af fragments [4k][8s][512]; phase 2/3 -> alpha [16][NN+8]
    __shared__ _Float16 sPool[4 * 8 * 512];   // 32 KB
    __shared__ _Float16 sA[4][DD];            // 2 KB
    __shared__ float sRedM[4][16];
    __shared__ float sRedS[4][16];
#define S_ALPHA(row, col) sPool[(row) * (NN + 8) + (col)]

    const int tid  = threadIdx.x;
    const int wave = tid >> 6;
    const int lane = tid & 63;
    const int c    = lane & 15;   // MFMA: A.m / B.n / C.col
    const int q    = lane >> 4;   // MFMA: k-quad; C.row = q*4+reg
    const int foff = q * 128 + c * 8;

    const int blk  = blockIdx.x;
    const int b    = (blk & 7) * 4 + ((blk >> 3) & 3);
    const int iblk = blk >> 5;
    const int i0   = iblk * 16;

    const _Float16* Hf   = h16f  + (size_t)b * NN * DD;
    const _Float16* Htf  = h16tf + (size_t)b * NN * DD;
    const int*      adjb = adj   + (size_t)b * NN * NN;
    const _Float16* hbase = Hf + (size_t)iblk * 8 * 512 + foff;

    sA[0][tid] = (_Float16)a0[tid];
    sA[1][tid] = (_Float16)a1[tid];
    sA[2][tid] = (_Float16)a2[tid];
    sA[3][tid] = (_Float16)a3[tid];
    __syncthreads();

    // ---- per-block af precompute: wave k builds af[k][s], s=0..7 ----
    {
        const int k = wave;
#pragma unroll
        for (int s = 0; s < 8; ++s) {
            half8 hf = *(const half8*)(hbase + s * 512);
            half8 aw = *(const half8*)(&sA[k][s * 32 + q * 8]);
            *(half8*)(&sPool[(k * 8 + s) * 512 + foff]) = hf * aw;
        }
    }
    __syncthreads();

    const int jbase = wave * 128;
    v4f S[8];   // selected scores: 16 rows x 128 j per wave

    // ---------------- phase 1: scores + select + leaky, 8 chunks of 16 j ----------------
#pragma unroll
    for (int g = 0; g < 8; ++g) {
        const int jg0 = jbase + g * 16;
        const _Float16* bbase = Hf + (size_t)(jg0 >> 4) * 8 * 512 + foff;

        // adj for this chunk, issued first
        int av[4];
#pragma unroll
        for (int r = 0; r < 4; ++r)
            av[r] = adjb[(size_t)(i0 + q * 4 + r) * NN + (jg0 + c)];

        // ALL 8 B-fragments of the chunk up-front: 8-deep outstanding loads
        half8 bfrag[8];
#pragma unroll
        for (int s = 0; s < 8; ++s)
            bfrag[s] = *(const half8*)(bbase + s * 512);

        v4f e[4];
#pragma unroll
        for (int k = 0; k < 4; ++k)
            e[k] = (v4f){0.f, 0.f, 0.f, 0.f};

#pragma unroll
        for (int s = 0; s < 8; ++s) {
#pragma unroll
            for (int k = 0; k < 4; ++k) {
                half8 af = *(const half8*)(&sPool[(k * 8 + s) * 512 + foff]);  // LDS
                e[k] = __builtin_amdgcn_mfma_f32_16x16x32_f16(af, bfrag[s], e[k], 0, 0, 0);
            }
        }
#pragma unroll
        for (int r = 0; r < 4; ++r) {
            const int v = av[r];
            float sc = (v == 1) ? e[0][r]
                     : (v == 2) ? e[1][r]
                     : (v == 3) ? e[2][r]
                     : (v == 4) ? e[3][r] : NEG_INF;
            sc = sc > 0.f ? sc : 0.2f * sc;
            S[g][r] = sc;
        }
    }

    // ---------------- phase 2: softmax over j (4-wave combine) ----------------
    float m4[4];
#pragma unroll
    for (int r = 0; r < 4; ++r) {
        float m = S[0][r];
#pragma unroll
        for (int t = 1; t < 8; ++t) m = fmaxf(m, S[t][r]);
#pragma unroll
        for (int off = 1; off < 16; off <<= 1)
            m = fmaxf(m, __shfl_xor(m, off, 64));
        m4[r] = m;
    }
    if (c == 0) {
#pragma unroll
        for (int r = 0; r < 4; ++r) sRedM[wave][q * 4 + r] = m4[r];
    }
    __syncthreads();   // also retires all af reads before alpha overwrites sPool

    float mf[4], sum4[4];
#pragma unroll
    for (int r = 0; r < 4; ++r) {
        float m = sRedM[0][q * 4 + r];
        m = fmaxf(m, sRedM[1][q * 4 + r]);
        m = fmaxf(m, sRedM[2][q * 4 + r]);
        m = fmaxf(m, sRedM[3][q * 4 + r]);
        mf[r]   = m;
        sum4[r] = 0.f;
    }
#pragma unroll
    for (int t = 0; t < 8; ++t) {
        const int j = jbase + t * 16 + c;
#pragma unroll
        for (int r = 0; r < 4; ++r) {
            float p = __expf(S[t][r] - mf[r]);   // NEG_INF path underflows to 0
            sum4[r] += p;
            S_ALPHA(q * 4 + r, j) = (_Float16)p;
        }
    }
#pragma unroll
    for (int r = 0; r < 4; ++r) {
#pragma unroll
        for (int off = 1; off < 16; off <<= 1)
            sum4[r] += __shfl_xor(sum4[r], off, 64);
    }
    if (c == 0) {
#pragma unroll
        for (int r = 0; r < 4; ++r) sRedS[wave][q * 4 + r] = sum4[r];
    }
    __syncthreads();

    // ---------------- phase 3: out = alpha @ H, wave = 64-d quarter, ks pairs ----------------
    v4f o[4];
#pragma unroll
    for (int nt = 0; nt < 4; ++nt) o[nt] = (v4f){0.f, 0.f, 0.f, 0.f};

#pragma unroll
    for (int kg = 0; kg < 8; ++kg) {
        half8 bf[2][4];
#pragma unroll
        for (int t2 = 0; t2 < 2; ++t2)
#pragma unroll
            for (int nt = 0; nt < 4; ++nt)
                bf[t2][nt] = *(const half8*)(Htf + (size_t)((wave * 4 + nt) * 16 + kg * 2 + t2) * 512 + foff);
#pragma unroll
        for (int t2 = 0; t2 < 2; ++t2) {
            half8 af = *(const half8*)(&S_ALPHA(c, (kg * 2 + t2) * 32 + q * 8));
#pragma unroll
            for (int nt = 0; nt < 4; ++nt)
                o[nt] = __builtin_amdgcn_mfma_f32_16x16x32_f16(af, bf[t2][nt], o[nt], 0, 0, 0);
        }
    }

    float* outb = out + (size_t)b * NN * DD;
    const int dq0 = wave * 64;
#pragma unroll
    for (int r = 0; r < 4; ++r) {
        const int irow = q * 4 + r;
        const float rinv = 1.f / (sRedS[0][irow] + sRedS[1][irow] +
                                  sRedS[2][irow] + sRedS[3][irow]);
#pragma unroll
        for (int nt = 0; nt < 4; ++nt) {
            const int d = dq0 + nt * 16 + c;
            outb[(size_t)(i0 + irow) * DD + d] = o[nt][r] * rinv;
        }
    }
#undef S_ALPHA
}

// ---------------- launcher ----------------
extern "C" void kernel_launch(void* const* d_in, const int* in_sizes, int n_in,
                              void* d_out, int out_size, void* d_ws, size_t ws_size,
                              hipStream_t stream) {
    const float* hidden = (const float*)d_in[0];
    const int*   adjp   = (const int*)d_in[1];
    const float* a0     = (const float*)d_in[2];
    const float* a1     = (const float*)d_in[3];
    const float* a2     = (const float*)d_in[4];
    const float* a3     = (const float*)d_in[5];
    float* outp = (float*)d_out;

    _Float16* h16f  = (_Float16*)d_ws;
    _Float16* h16tf = h16f + (size_t)BB * NN * DD;

    dim3 g1(DD / 32, NN / 32, BB);
    cvt_kernel<<<g1, 128, 0, stream>>>(hidden, h16f, h16tf);

    gat_kernel<<<BB * (NN / 16), 256, 0, stream>>>(h16f, h16tf, adjp, a0, a1, a2, a3, outp);
}

// Round 10
// 131.144 us; speedup vs baseline: 1.5716x; 1.5716x over previous
//
#include <hip/hip_runtime.h>
#include <hip/hip_fp16.h>

#define BB 32
#define NN 512
#define DD 256
#define NEG_INF -9e15f

typedef _Float16 half8 __attribute__((ext_vector_type(8)));
typedef float v4f __attribute__((ext_vector_type(4)));
typedef float f4v __attribute__((ext_vector_type(4)));

// Fragment-swizzled layouts (16x16x32 MFMA, lane = q*16+c reads 16B at laneID*16B):
//  h16f : element h[b][n][d] at ((b*32 + n/16)*8 + d/32)*512 + ((d%32)/8)*128 + (n%16)*8 + d%8
//  h16tf: element h[b][j][d] at ((b*16 + d/16)*16 + j/32)*512 + ((j%32)/8)*128 + (d%16)*8 + j%8

// ---------------- pre-kernel: fp32 -> fp16 convert into swizzled layouts ----------------
__global__ __launch_bounds__(128) void cvt_kernel(const float* __restrict__ h,
                                                  _Float16* __restrict__ h16f,
                                                  _Float16* __restrict__ h16tf) {
    __shared__ _Float16 tile[32][36];
    const int d0 = blockIdx.x * 32;
    const int n0 = blockIdx.y * 32;
    const int b  = blockIdx.z;
    const int t  = threadIdx.x;

    const int nl = t >> 2;          // 0..31
    const int dq = (t & 3) * 8;     // 0,8,16,24
    const float* src = h + ((size_t)b * NN + (n0 + nl)) * DD + d0 + dq;
    f4v v0 = *(const f4v*)(src);
    f4v v1 = *(const f4v*)(src + 4);
    half8 hv = { (_Float16)v0.x, (_Float16)v0.y, (_Float16)v0.z, (_Float16)v0.w,
                 (_Float16)v1.x, (_Float16)v1.y, (_Float16)v1.z, (_Float16)v1.w };

    {
        const size_t off = ((size_t)(b * 32 + ((n0 + nl) >> 4)) * 8 + (d0 >> 5)) * 512
                         + (dq >> 3) * 128 + ((n0 + nl) & 15) * 8;
        *(half8*)(h16f + off) = hv;
    }
    *(half8*)(&tile[nl][dq]) = hv;
    __syncthreads();

    const int dl = t >> 2;          // 0..31
    const int nq = (t & 3) * 8;     // 0,8,16,24
    half8 o = { tile[nq][dl],     tile[nq + 1][dl], tile[nq + 2][dl], tile[nq + 3][dl],
                tile[nq + 4][dl], tile[nq + 5][dl], tile[nq + 6][dl], tile[nq + 7][dl] };
    {
        const size_t off = ((size_t)(b * 16 + ((d0 + dl) >> 4)) * 16 + (n0 >> 5)) * 512
                         + (nq >> 3) * 128 + ((d0 + dl) & 15) * 8;
        *(half8*)(h16tf + off) = o;
    }
}

// ---------------- fused GAT kernel ----------------
// Grid: BB*(NN/16) = 1024 blocks of 256 threads. Block = (b, 16-row i-block).
// XCD swizzle: XCD x (= blk&7) owns batches 4x..4x+3 (L2-resident fragments).
// (256,2): 256-reg unified budget -> 16-deep flat batch loads, no spill
// (at (256,4) the 64-arch-VGPR split spills anything past R8's shape — R2/R6/R7/R9).
__global__ __launch_bounds__(256, 2) void gat_kernel(
    const _Float16* __restrict__ h16f,   // swizzled [B][N/16][D/32][4][16][8]
    const _Float16* __restrict__ h16tf,  // swizzled [B][D/16][N/32][4][16][8]
    const int* __restrict__ adj,         // [B][N][N]
    const float* __restrict__ a0, const float* __restrict__ a1,
    const float* __restrict__ a2, const float* __restrict__ a3,
    float* __restrict__ out)             // [B][N][D]
{
    // union: phase 1 -> af fragments [4k][8s][512]; phase 2/3 -> alpha [16][NN+8]
    __shared__ _Float16 sPool[4 * 8 * 512];   // 32 KB
    __shared__ _Float16 sA[4][DD];            // 2 KB
    __shared__ float sRedM[4][16];
    __shared__ float sRedS[4][16];
#define S_ALPHA(row, col) sPool[(row) * (NN + 8) + (col)]

    const int tid  = threadIdx.x;
    const int wave = tid >> 6;
    const int lane = tid & 63;
    const int c    = lane & 15;   // MFMA: A.m / B.n / C.col
    const int q    = lane >> 4;   // MFMA: k-quad; C.row = q*4+reg
    const int foff = q * 128 + c * 8;

    const int blk  = blockIdx.x;
    const int b    = (blk & 7) * 4 + ((blk >> 3) & 3);
    const int iblk = blk >> 5;
    const int i0   = iblk * 16;

    const _Float16* Hf   = h16f  + (size_t)b * NN * DD;
    const _Float16* Htf  = h16tf + (size_t)b * NN * DD;
    const int*      adjb = adj   + (size_t)b * NN * NN;
    const _Float16* hbase = Hf + (size_t)iblk * 8 * 512 + foff;

    sA[0][tid] = (_Float16)a0[tid];
    sA[1][tid] = (_Float16)a1[tid];
    sA[2][tid] = (_Float16)a2[tid];
    sA[3][tid] = (_Float16)a3[tid];
    __syncthreads();

    // ---- per-block af precompute: wave k builds af[k][s], s=0..7 ----
    {
        const int k = wave;
#pragma unroll
        for (int s = 0; s < 8; ++s) {
            half8 hf = *(const half8*)(hbase + s * 512);
            half8 aw = *(const half8*)(&sA[k][s * 32 + q * 8]);
            *(half8*)(&sPool[(k * 8 + s) * 512 + foff]) = hf * aw;
        }
    }
    __syncthreads();

    const int jbase = wave * 128;
    v4f S[8];   // selected scores: 16 rows x 128 j per wave

    // ---------------- phase 1: scores + select + leaky, 4 chunks of 32 j ----------------
#pragma unroll
    for (int g = 0; g < 4; ++g) {
        const int jg0 = jbase + g * 32;
        const _Float16* bbase = Hf + (size_t)(jg0 >> 4) * 8 * 512 + foff;

        // adj for this chunk, issued first
        int av[2][4];
#pragma unroll
        for (int jt = 0; jt < 2; ++jt)
#pragma unroll
            for (int r = 0; r < 4; ++r)
                av[jt][r] = adjb[(size_t)(i0 + q * 4 + r) * NN + (jg0 + jt * 16 + c)];

        // ALL 16 B-fragments of the chunk up-front: 16-deep outstanding loads
        half8 bfrag[2][8];
#pragma unroll
        for (int jt = 0; jt < 2; ++jt)
#pragma unroll
            for (int s = 0; s < 8; ++s)
                bfrag[jt][s] = *(const half8*)(bbase + (jt * 8 + s) * 512);

        v4f e[4][2];
#pragma unroll
        for (int k = 0; k < 4; ++k)
#pragma unroll
            for (int jt = 0; jt < 2; ++jt)
                e[k][jt] = (v4f){0.f, 0.f, 0.f, 0.f};

#pragma unroll
        for (int s = 0; s < 8; ++s) {
#pragma unroll
            for (int k = 0; k < 4; ++k) {
                half8 af = *(const half8*)(&sPool[(k * 8 + s) * 512 + foff]);  // LDS
                e[k][0] = __builtin_amdgcn_mfma_f32_16x16x32_f16(af, bfrag[0][s], e[k][0], 0, 0, 0);
                e[k][1] = __builtin_amdgcn_mfma_f32_16x16x32_f16(af, bfrag[1][s], e[k][1], 0, 0, 0);
            }
        }
#pragma unroll
        for (int jt = 0; jt < 2; ++jt) {
#pragma unroll
            for (int r = 0; r < 4; ++r) {
                const int v = av[jt][r];
                float sc = (v == 1) ? e[0][jt][r]
                         : (v == 2) ? e[1][jt][r]
                         : (v == 3) ? e[2][jt][r]
                         : (v == 4) ? e[3][jt][r] : NEG_INF;
                sc = sc > 0.f ? sc : 0.2f * sc;
                S[g * 2 + jt][r] = sc;
            }
        }
    }

    // ---------------- phase 2: softmax over j (4-wave combine) ----------------
    float m4[4];
#pragma unroll
    for (int r = 0; r < 4; ++r) {
        float m = S[0][r];
#pragma unroll
        for (int t = 1; t < 8; ++t) m = fmaxf(m, S[t][r]);
#pragma unroll
        for (int off = 1; off < 16; off <<= 1)
            m = fmaxf(m, __shfl_xor(m, off, 64));
        m4[r] = m;
    }
    if (c == 0) {
#pragma unroll
        for (int r = 0; r < 4; ++r) sRedM[wave][q * 4 + r] = m4[r];
    }
    __syncthreads();   // also retires all af reads before alpha overwrites sPool

    float mf[4], sum4[4];
#pragma unroll
    for (int r = 0; r < 4; ++r) {
        float m = sRedM[0][q * 4 + r];
        m = fmaxf(m, sRedM[1][q * 4 + r]);
        m = fmaxf(m, sRedM[2][q * 4 + r]);
        m = fmaxf(m, sRedM[3][q * 4 + r]);
        mf[r]   = m;
        sum4[r] = 0.f;
    }
#pragma unroll
    for (int t = 0; t < 8; ++t) {
        const int j = jbase + t * 16 + c;
#pragma unroll
        for (int r = 0; r < 4; ++r) {
            float p = __expf(S[t][r] - mf[r]);   // NEG_INF path underflows to 0
            sum4[r] += p;
            S_ALPHA(q * 4 + r, j) = (_Float16)p;
        }
    }
#pragma unroll
    for (int r = 0; r < 4; ++r) {
#pragma unroll
        for (int off = 1; off < 16; off <<= 1)
            sum4[r] += __shfl_xor(sum4[r], off, 64);
    }
    if (c == 0) {
#pragma unroll
        for (int r = 0; r < 4; ++r) sRedS[wave][q * 4 + r] = sum4[r];
    }
    __syncthreads();

    // ---------------- phase 3: out = alpha @ H, wave = 64-d quarter, ks groups of 4 ----------------
    v4f o[4];
#pragma unroll
    for (int nt = 0; nt < 4; ++nt) o[nt] = (v4f){0.f, 0.f, 0.f, 0.f};

#pragma unroll
    for (int kg = 0; kg < 4; ++kg) {
        half8 bf[4][4];   // 16 loads up-front
#pragma unroll
        for (int t4 = 0; t4 < 4; ++t4)
#pragma unroll
            for (int nt = 0; nt < 4; ++nt)
                bf[t4][nt] = *(const half8*)(Htf + (size_t)((wave * 4 + nt) * 16 + kg * 4 + t4) * 512 + foff);
#pragma unroll
        for (int t4 = 0; t4 < 4; ++t4) {
            half8 af = *(const half8*)(&S_ALPHA(c, (kg * 4 + t4) * 32 + q * 8));
#pragma unroll
            for (int nt = 0; nt < 4; ++nt)
                o[nt] = __builtin_amdgcn_mfma_f32_16x16x32_f16(af, bf[t4][nt], o[nt], 0, 0, 0);
        }
    }

    float* outb = out + (size_t)b * NN * DD;
    const int dq0 = wave * 64;
#pragma unroll
    for (int r = 0; r < 4; ++r) {
        const int irow = q * 4 + r;
        const float rinv = 1.f / (sRedS[0][irow] + sRedS[1][irow] +
                                  sRedS[2][irow] + sRedS[3][irow]);
#pragma unroll
        for (int nt = 0; nt < 4; ++nt) {
            const int d = dq0 + nt * 16 + c;
            outb[(size_t)(i0 + irow) * DD + d] = o[nt][r] * rinv;
        }
    }
#undef S_ALPHA
}

// ---------------- launcher ----------------
extern "C" void kernel_launch(void* const* d_in, const int* in_sizes, int n_in,
                              void* d_out, int out_size, void* d_ws, size_t ws_size,
                              hipStream_t stream) {
    const float* hidden = (const float*)d_in[0];
    const int*   adjp   = (const int*)d_in[1];
    const float* a0     = (const float*)d_in[2];
    const float* a1     = (const float*)d_in[3];
    const float* a2     = (const float*)d_in[4];
    const float* a3     = (const float*)d_in[5];
    float* outp = (float*)d_out;

    _Float16* h16f  = (_Float16*)d_ws;
    _Float16* h16tf = h16f + (size_t)BB * NN * DD;

    dim3 g1(DD / 32, NN / 32, BB);
    cvt_kernel<<<g1, 128, 0, stream>>>(hidden, h16f, h16tf);

    gat_kernel<<<BB * (NN / 16), 256, 0, stream>>>(h16f, h16tf, adjp, a0, a1, a2, a3, outp);
}